// Round 6
// baseline (610.528 us; speedup 1.0000x reference)
//
#include <hip/hip_runtime.h>
#include <hip/hip_bf16.h>

#define NC 64      // channels / signal dim
#define NA 512     // dictionary atoms
#define KS 5       // sparsity

// ---- workspace layout in DOUBLES, total 327681 * 8 B = 2.62 MB ----
#define WS_DN   0        // Dn_d  [NC][NA]
#define WS_DNT  32768    // DnT_d [NA][NC]
#define WS_G    65536    // G_d   [NA][NA]
#define WS_ACC  327680   // loss accumulator (double)

// out layout (FLOAT32): z_dl[2097152] | loss[1] | support[163840] | coeffs[163840]
#define OUT_LOSS 2097152
#define OUT_SUP  2097153
#define OUT_COF  2260993

__global__ void norm_kernel(const float* __restrict__ D,
                            double* __restrict__ Dn, double* __restrict__ DnT) {
  int n = blockIdx.x * blockDim.x + threadIdx.x;
  if (n >= NA) return;
  double s = 0.0;
  for (int c = 0; c < NC; ++c) {
    double v = (double)D[c * NA + n];
    s += v * v;
  }
  double den = fmax(sqrt(s), 1e-10);
  for (int c = 0; c < NC; ++c) {
    double v = (double)D[c * NA + n] / den;
    Dn[c * NA + n]  = v;
    DnT[n * NC + c] = v;
  }
}

__global__ void gram_kernel(const double* __restrict__ Dn,
                            double* __restrict__ G, double* __restrict__ accum) {
  __shared__ double col[NC];
  int i = blockIdx.x, t = threadIdx.x;
  if (t < NC) col[t] = Dn[t * NA + i];
  if (i == 0 && t == 0) *accum = 0.0;
  __syncthreads();
  double s = 0.0;
#pragma unroll
  for (int c = 0; c < NC; ++c) s += col[c] * Dn[c * NA + t];
  G[(size_t)i * NA + t] = s;
}

// One wave per signal. 4 waves (4 signals) per 256-thread block. Grid 8192.
// Lane owns atoms {lane + 64*i, i=0..7}  -> all G / Dn accesses coalesced.
__global__ __launch_bounds__(256) void omp_kernel(
    const float* __restrict__ z, const double* __restrict__ Dn,
    const double* __restrict__ DnT, const double* __restrict__ G,
    float* __restrict__ out, double* __restrict__ accum) {
  __shared__ float xs[4][NC];   // 1 KB
  const int t = threadIdx.x, lane = t & 63, wv = t >> 6;
  const int m0 = blockIdx.x * 4;

  // 4 signals share one (b,h) row of z_e; w in [w0, w0+4)
  {
    const int bh = m0 >> 6;
    const int b = bh >> 6, h = bh & 63, w0 = m0 & 63;
    const size_t zbase = (size_t)b * 262144 + (size_t)h * 64 + w0;
    const int c = t >> 2, s = t & 3;     // 16B-contiguous segments
    xs[s][c] = z[zbase + (size_t)c * 4096 + s];
  }
  __syncthreads();

  const int m = m0 + wv;

  // ---- phase 1: h_bar for this wave's signal, f64, atom n = lane + 64*i
  double acc[8];
#pragma unroll
  for (int i = 0; i < 8; ++i) acc[i] = 0.0;
  for (int c = 0; c < NC; ++c) {
    const double xv = (double)xs[wv][c];
    const double* dr = Dn + (size_t)c * NA + lane;
#pragma unroll
    for (int i = 0; i < 8; ++i) acc[i] += xv * dr[i * 64];
  }

  // ---- phase 2: OMP iterations, all lanes in lock-step
  double h8[8];
#pragma unroll
  for (int i = 0; i < 8; ++i) h8[i] = acc[i];
  unsigned msk = 0xFFu;
  int I[KS];
  double Lm[15], gam[KS], hbI[KS], grow[4][8];

#pragma unroll
  for (int kk = 0; kk < KS; ++kk) {
    // argmax |h|*mask; first-occurrence (smallest index) tie-break
    double bv = -1.0; int bn = 0;
#pragma unroll
    for (int i = 0; i < 8; ++i) {
      double v = ((msk >> i) & 1u) ? fabs(h8[i]) : 0.0;
      if (v > bv || (v == bv && (lane + (i << 6)) < bn)) { bv = v; bn = lane + (i << 6); }
    }
#pragma unroll
    for (int off = 1; off < 64; off <<= 1) {
      double ov = __shfl_xor(bv, off);
      int    on = __shfl_xor(bn, off);
      if (ov > bv || (ov == bv && on < bn)) { bv = ov; bn = on; }
    }
    const int idx = bn;                              // wave-uniform
    if ((idx & 63) == lane) msk &= ~(1u << (idx >> 6));

    // h_bar[idx] via cooperative coalesced dot  (DnT row idx = atom idx)
    {
      double p = (double)xs[wv][lane] * DnT[(size_t)idx * NC + lane];
#pragma unroll
      for (int off = 1; off < 64; off <<= 1) p += __shfl_xor(p, off);
      hbI[kk] = p;
    }

    // Cholesky update (replicated on all lanes; broadcast G reads)
    if (kk == 0) {
      Lm[0] = 1.0;
    } else {
      double Gc[4], w_[4];
#pragma unroll
      for (int j = 0; j < 4; ++j) if (j < kk) Gc[j] = G[(size_t)I[j] * NA + idx];
#pragma unroll
      for (int i = 0; i < 4; ++i) if (i < kk) {
        double ssum = Gc[i];
#pragma unroll
        for (int j = 0; j < 4; ++j) if (j < i) ssum -= Lm[i*(i+1)/2 + j] * w_[j];
        w_[i] = ssum / Lm[i*(i+1)/2 + i];
      }
      double ww = 0.0;
#pragma unroll
      for (int i = 0; i < 4; ++i) if (i < kk) ww += w_[i] * w_[i];
      double corner = sqrt(fmax(1.0 - ww, 1e-12));
#pragma unroll
      for (int j = 0; j < 4; ++j) if (j < kk) Lm[kk*(kk+1)/2 + j] = w_[j];
      Lm[kk*(kk+1)/2 + kk] = corner;
    }
    I[kk] = idx;

    // gamma = cho_solve((L, lower), h_bar[I])
    double y[KS];
#pragma unroll
    for (int i = 0; i < KS; ++i) if (i <= kk) {
      double b_ = hbI[i];
#pragma unroll
      for (int j = 0; j < KS; ++j) if (j < i) b_ -= Lm[i*(i+1)/2 + j] * y[j];
      y[i] = b_ / Lm[i*(i+1)/2 + i];
    }
#pragma unroll
    for (int i = KS - 1; i >= 0; --i) if (i <= kk) {
      double g_ = y[i];
#pragma unroll
      for (int j = 0; j < KS; ++j) if (j > i && j <= kk) g_ -= Lm[j*(j+1)/2 + i] * gam[j];
      gam[i] = g_ / Lm[i*(i+1)/2 + i];
    }

    // h = h_bar - gamma^T G[I]   (G row idx cached; coalesced reads)
    if (kk < 4) {
      const double* gr = G + (size_t)idx * NA + lane;
#pragma unroll
      for (int i = 0; i < 8; ++i) grow[kk][i] = gr[i * 64];
#pragma unroll
      for (int i = 0; i < 8; ++i) {
        double beta = 0.0;
#pragma unroll
        for (int j = 0; j < 4; ++j) if (j <= kk) beta += gam[j] * grow[j][i];
        h8[i] = acc[i] - beta;
      }
    }
  }

  // ---- epilogue
  const int b = m >> 12, hh = (m >> 6) & 63, wq = m & 63;
  double r = 0.0;
#pragma unroll
  for (int j = 0; j < KS; ++j) r += gam[j] * DnT[(size_t)I[j] * NC + lane];
  const double e = (double)xs[wv][lane];
  const double d = r - e;                      // z_dl - z_e
  out[(size_t)b * 262144 + (size_t)lane * 4096 + (size_t)hh * 64 + wq] =
      (float)(e + d);                          // z_e + (z_dl - z_e)
  double sq = d * d;
#pragma unroll
  for (int off = 1; off < 64; off <<= 1) sq += __shfl_xor(sq, off);
  if (lane == 0) atomicAdd(accum, sq);

  // support / coeffs: constant-index selection chains only
  if (lane < KS) {
    int    iv = I[0];
    double gv = gam[0];
    if (lane == 1) { iv = I[1]; gv = gam[1]; }
    if (lane == 2) { iv = I[2]; gv = gam[2]; }
    if (lane == 3) { iv = I[3]; gv = gam[3]; }
    if (lane == 4) { iv = I[4]; gv = gam[4]; }
    out[OUT_SUP + (size_t)m * KS + lane] = (float)iv;
    out[OUT_COF + (size_t)m * KS + lane] = (float)gv;
  }
}

__global__ void final_kernel(const double* __restrict__ accum, float* __restrict__ out) {
  double mse = *accum / 2097152.0;
  out[OUT_LOSS] = (float)(mse + 0.25 * mse);
}

extern "C" void kernel_launch(void* const* d_in, const int* in_sizes, int n_in,
                              void* d_out, int out_size, void* d_ws, size_t ws_size,
                              hipStream_t stream) {
  const float* z_e = (const float*)d_in[0];
  const float* dic = (const float*)d_in[1];
  float* out = (float*)d_out;
  double* ws = (double*)d_ws;
  double* Dn   = ws + WS_DN;
  double* DnT  = ws + WS_DNT;
  double* G    = ws + WS_G;
  double* accu = ws + WS_ACC;

  hipLaunchKernelGGL(norm_kernel,  dim3(1),    dim3(512), 0, stream, dic, Dn, DnT);
  hipLaunchKernelGGL(gram_kernel,  dim3(NA),   dim3(NA),  0, stream, Dn, G, accu);
  hipLaunchKernelGGL(omp_kernel,   dim3(8192), dim3(256), 0, stream,
                     z_e, Dn, DnT, G, out, accu);
  hipLaunchKernelGGL(final_kernel, dim3(1),    dim3(1),   0, stream, accu, out);
}

// Round 7
// 286.625 us; speedup vs baseline: 2.1301x; 2.1301x over previous
//
#include <hip/hip_runtime.h>

#define NC 64      // channels / signal dim
#define NA 512     // dictionary atoms
#define KS 5       // sparsity

// ---- workspace layout in DOUBLES, total 327681 * 8 B = 2.62 MB ----
#define WS_DN   0        // Dn_d  [NC][NA]
#define WS_DNT  32768    // DnT_d [NA][NC]
#define WS_G    65536    // G_d   [NA][NA]
#define WS_ACC  327680   // loss accumulator (double)

// out layout (FLOAT32): z_dl[2097152] | loss[1] | support[163840] | coeffs[163840]
#define OUT_LOSS 2097152
#define OUT_SUP  2097153
#define OUT_COF  2260993

__global__ void norm_kernel(const float* __restrict__ D,
                            double* __restrict__ Dn, double* __restrict__ DnT) {
  int n = blockIdx.x * blockDim.x + threadIdx.x;
  if (n >= NA) return;
  double s = 0.0;
  for (int c = 0; c < NC; ++c) {
    double v = (double)D[c * NA + n];
    s += v * v;
  }
  double den = fmax(sqrt(s), 1e-10);
  for (int c = 0; c < NC; ++c) {
    double v = (double)D[c * NA + n] / den;
    Dn[c * NA + n]  = v;
    DnT[n * NC + c] = v;
  }
}

__global__ void gram_kernel(const double* __restrict__ Dn,
                            double* __restrict__ G, double* __restrict__ accum) {
  __shared__ double col[NC];
  int i = blockIdx.x, t = threadIdx.x;
  if (t < NC) col[t] = Dn[t * NA + i];
  if (i == 0 && t == 0) *accum = 0.0;
  __syncthreads();
  double s = 0.0;
#pragma unroll
  for (int c = 0; c < NC; ++c) s += col[c] * Dn[c * NA + t];
  G[(size_t)i * NA + t] = s;
}

// 8 signals per block (2 per wave), grid 4096.
// Lane owns atom pairs {2*lane + 128*i + p : i=0..3, p=0..1}; slot s = i*2+p.
__global__ __launch_bounds__(256) void omp_kernel(
    const float* __restrict__ z, const double* __restrict__ Dn,
    const double* __restrict__ DnT, const double* __restrict__ G,
    float* __restrict__ out, double* __restrict__ accum) {
  __shared__ float  xs[8][NC];       // 2 KB   signals
  __shared__ double buf[8 * NA];     // 32 KB  Dn chunk, then h_bar[8][512]
  __shared__ float  zout[NC][8];     // 2 KB   z_dl staging for coalesced store
  __shared__ double wsq[8];          // per-signal squared-error sums
  const int t = threadIdx.x, lane = t & 63, wv = t >> 6;
  const int m0 = blockIdx.x * 8;
  const int bh = m0 >> 6, b = bh >> 6, h = bh & 63, w0 = m0 & 63;
  const size_t zbase = (size_t)b * 262144 + (size_t)h * 64 + w0;

  // load 8 signals (shared (b,h) row, w in [w0,w0+8))
  for (int j = t; j < 8 * NC; j += 256) {
    int c = j >> 3, s = j & 7;
    xs[s][c] = z[zbase + (size_t)c * 4096 + s];
  }

  // ---- phase 1: f64 h_bar GEMM, Dn staged through LDS in 8-row chunks
  double acc[2][8];
#pragma unroll
  for (int s = 0; s < 2; ++s)
#pragma unroll
    for (int i = 0; i < 8; ++i) acc[s][i] = 0.0;

  const double2* Dn2 = (const double2*)Dn;
  double2* buf2 = (double2*)buf;
  for (int ch = 0; ch < 8; ++ch) {
    __syncthreads();                       // previous chunk fully consumed
#pragma unroll
    for (int p = 0; p < 8; ++p) {          // 2048 double2 per chunk, coalesced
      int j = p * 256 + t;
      buf2[j] = Dn2[ch * 2048 + j];
    }
    __syncthreads();
#pragma unroll
    for (int c8 = 0; c8 < 8; ++c8) {
      int c = ch * 8 + c8;
      double x0 = (double)xs[wv * 2 + 0][c];
      double x1 = (double)xs[wv * 2 + 1][c];
#pragma unroll
      for (int i = 0; i < 4; ++i) {
        double2 dv = buf2[c8 * 256 + (i << 6) + lane];
        acc[0][i * 2]     += x0 * dv.x; acc[0][i * 2 + 1] += x0 * dv.y;
        acc[1][i * 2]     += x1 * dv.x; acc[1][i * 2 + 1] += x1 * dv.y;
      }
    }
  }
  __syncthreads();                         // all waves done reading Dn chunks
  // park h_bar in LDS (per-wave region; only read back by the owning wave)
#pragma unroll
  for (int si = 0; si < 2; ++si)
#pragma unroll
    for (int i = 0; i < 4; ++i) {
      double2 v; v.x = acc[si][i * 2]; v.y = acc[si][i * 2 + 1];
      buf2[(size_t)(wv * 2 + si) * 256 + (i << 6) + lane] = v;
    }

  // ---- phase 2: OMP, one wave per signal (2 sequential per wave)
#pragma unroll
  for (int si = 0; si < 2; ++si) {
    const int sig = wv * 2 + si, m = m0 + sig;
    const double* hbs = buf + (size_t)sig * NA;
    double h8[8];
#pragma unroll
    for (int i = 0; i < 8; ++i) h8[i] = acc[si][i];
    unsigned msk = 0xFFu;
    int I[KS];
    double Lm[15], rd[KS], gam[KS], hbI[KS], grow[4][8];

#pragma unroll
    for (int kk = 0; kk < KS; ++kk) {
      // argmax |h|*mask; first-occurrence (smallest global index) tie-break
      double bv = -1.0; int bn = 0;
#pragma unroll
      for (int s = 0; s < 8; ++s) {
        int a = ((s >> 1) << 7) + 2 * lane + (s & 1);
        double v = ((msk >> s) & 1u) ? fabs(h8[s]) : 0.0;
        if (v > bv || (v == bv && a < bn)) { bv = v; bn = a; }
      }
#pragma unroll
      for (int off = 1; off < 64; off <<= 1) {
        double ov = __shfl_xor(bv, off);
        int    on = __shfl_xor(bn, off);
        if (ov > bv || (ov == bv && on < bn)) { bv = ov; bn = on; }
      }
      const int idx = bn;                              // wave-uniform
      if (((idx & 127) >> 1) == lane)
        msk &= ~(1u << ((((idx >> 7)) << 1) | (idx & 1)));

      hbI[kk] = hbs[idx];                              // LDS broadcast read

      // G row for idx (coalesced 16B/lane); needed for h update, issue early
      if (kk < 4) {
        const double2* g2 = (const double2*)(G + (size_t)idx * NA);
#pragma unroll
        for (int i = 0; i < 4; ++i) {
          double2 g = g2[(i << 6) + lane];
          grow[kk][i * 2] = g.x; grow[kk][i * 2 + 1] = g.y;
        }
      }

      // Cholesky update (replicated on all lanes; reciprocal-diag solves)
      if (kk == 0) {
        Lm[0] = 1.0; rd[0] = 1.0;
      } else {
        double Gc[4], w_[4];
#pragma unroll
        for (int j = 0; j < 4; ++j) if (j < kk) Gc[j] = G[(size_t)I[j] * NA + idx];
#pragma unroll
        for (int i = 0; i < 4; ++i) if (i < kk) {
          double ssum = Gc[i];
#pragma unroll
          for (int j = 0; j < 4; ++j) if (j < i) ssum -= Lm[i*(i+1)/2 + j] * w_[j];
          w_[i] = ssum * rd[i];
        }
        double ww = 0.0;
#pragma unroll
        for (int i = 0; i < 4; ++i) if (i < kk) ww += w_[i] * w_[i];
        double corner = sqrt(fmax(1.0 - ww, 1e-12));
#pragma unroll
        for (int j = 0; j < 4; ++j) if (j < kk) Lm[kk*(kk+1)/2 + j] = w_[j];
        Lm[kk*(kk+1)/2 + kk] = corner;
        rd[kk] = 1.0 / corner;
      }
      I[kk] = idx;

      // gamma = cho_solve((L, lower), h_bar[I])
      double y[KS];
#pragma unroll
      for (int i = 0; i < KS; ++i) if (i <= kk) {
        double b_ = hbI[i];
#pragma unroll
        for (int j = 0; j < KS; ++j) if (j < i) b_ -= Lm[i*(i+1)/2 + j] * y[j];
        y[i] = b_ * rd[i];
      }
#pragma unroll
      for (int i = KS - 1; i >= 0; --i) if (i <= kk) {
        double g_ = y[i];
#pragma unroll
        for (int j = 0; j < KS; ++j) if (j > i && j <= kk) g_ -= Lm[j*(j+1)/2 + i] * gam[j];
        gam[i] = g_ * rd[i];
      }

      // h = h_bar - gamma^T G[I]
      if (kk < 4) {
#pragma unroll
        for (int s = 0; s < 8; ++s) {
          double beta = 0.0;
#pragma unroll
          for (int j = 0; j < 4; ++j) if (j <= kk) beta += gam[j] * grow[j][s];
          h8[s] = acc[si][s] - beta;
        }
      }
    }

    // ---- epilogue for this signal
    double r = 0.0;
#pragma unroll
    for (int j = 0; j < KS; ++j) r += gam[j] * DnT[(size_t)I[j] * NC + lane];
    const double e = (double)xs[sig][lane];
    const double d = r - e;                      // z_dl - z_e
    zout[lane][sig] = (float)(e + d);            // z_e + (z_dl - z_e)
    double sq = d * d;
#pragma unroll
    for (int off = 1; off < 64; off <<= 1) sq += __shfl_xor(sq, off);
    if (lane == 0) wsq[sig] = sq;

    // support / coeffs: constant-index selection chains only
    if (lane < KS) {
      int    iv = I[0];
      double gv = gam[0];
      if (lane == 1) { iv = I[1]; gv = gam[1]; }
      if (lane == 2) { iv = I[2]; gv = gam[2]; }
      if (lane == 3) { iv = I[3]; gv = gam[3]; }
      if (lane == 4) { iv = I[4]; gv = gam[4]; }
      out[OUT_SUP + (size_t)m * KS + lane] = (float)iv;
      out[OUT_COF + (size_t)m * KS + lane] = (float)gv;
    }
  }

  __syncthreads();
  // coalesced z_dl store: [c][s] tiles, 32B segments
  for (int j = t; j < 8 * NC; j += 256) {
    int c = j >> 3, s = j & 7;
    out[zbase + (size_t)c * 4096 + s] = zout[c][s];
  }
  if (t == 0) {
    double ssum = 0.0;
#pragma unroll
    for (int i = 0; i < 8; ++i) ssum += wsq[i];
    atomicAdd(accum, ssum);
  }
}

__global__ void final_kernel(const double* __restrict__ accum, float* __restrict__ out) {
  double mse = *accum / 2097152.0;
  out[OUT_LOSS] = (float)(mse + 0.25 * mse);
}

extern "C" void kernel_launch(void* const* d_in, const int* in_sizes, int n_in,
                              void* d_out, int out_size, void* d_ws, size_t ws_size,
                              hipStream_t stream) {
  const float* z_e = (const float*)d_in[0];
  const float* dic = (const float*)d_in[1];
  float* out = (float*)d_out;
  double* ws = (double*)d_ws;
  double* Dn   = ws + WS_DN;
  double* DnT  = ws + WS_DNT;
  double* G    = ws + WS_G;
  double* accu = ws + WS_ACC;

  hipLaunchKernelGGL(norm_kernel,  dim3(1),    dim3(512), 0, stream, dic, Dn, DnT);
  hipLaunchKernelGGL(gram_kernel,  dim3(NA),   dim3(NA),  0, stream, Dn, G, accu);
  hipLaunchKernelGGL(omp_kernel,   dim3(4096), dim3(256), 0, stream,
                     z_e, Dn, DnT, G, out, accu);
  hipLaunchKernelGGL(final_kernel, dim3(1),    dim3(1),   0, stream, accu, out);
}

// Round 8
// 270.404 us; speedup vs baseline: 2.2578x; 1.0600x over previous
//
#include <hip/hip_runtime.h>

#define NC 64      // channels / signal dim
#define NA 512     // dictionary atoms
#define KS 5       // sparsity

// ---- workspace layout in DOUBLES, total 327681 * 8 B = 2.62 MB ----
#define WS_DN   0        // Dn_d  [NC][NA]
#define WS_DNT  32768    // DnT_d [NA][NC]
#define WS_G    65536    // G_d   [NA][NA]
#define WS_ACC  327680   // loss accumulator (double)

// out layout (FLOAT32): z_dl[2097152] | loss[1] | support[163840] | coeffs[163840]
#define OUT_LOSS 2097152
#define OUT_SUP  2097153
#define OUT_COF  2260993

__global__ void norm_kernel(const float* __restrict__ D,
                            double* __restrict__ Dn, double* __restrict__ DnT) {
  int n = blockIdx.x * blockDim.x + threadIdx.x;
  if (n >= NA) return;
  double s = 0.0;
  for (int c = 0; c < NC; ++c) {
    double v = (double)D[c * NA + n];
    s += v * v;
  }
  double den = fmax(sqrt(s), 1e-10);
  for (int c = 0; c < NC; ++c) {
    double v = (double)D[c * NA + n] / den;
    Dn[c * NA + n]  = v;
    DnT[n * NC + c] = v;
  }
}

__global__ void gram_kernel(const double* __restrict__ Dn,
                            double* __restrict__ G, double* __restrict__ accum) {
  __shared__ double col[NC];
  int i = blockIdx.x, t = threadIdx.x;
  if (t < NC) col[t] = Dn[t * NA + i];
  if (i == 0 && t == 0) *accum = 0.0;
  __syncthreads();
  double s = 0.0;
#pragma unroll
  for (int c = 0; c < NC; ++c) s += col[c] * Dn[c * NA + t];
  G[(size_t)i * NA + t] = s;
}

// 8 signals per block (2 per wave), grid 4096.
// Lane owns atom pairs {2*lane + 128*i + p : i=0..3, p=0..1}; slot s = i*2+p
// maps to atom a = (s>>1)*128 + 2*lane + (s&1). Parked h_bar double index == a.
__global__ __launch_bounds__(256) void omp_kernel(
    const float* __restrict__ z, const double* __restrict__ Dn,
    const double* __restrict__ DnT, const double* __restrict__ G,
    float* __restrict__ out, double* __restrict__ accum) {
  __shared__ float  xs[8][NC];                   // 2 KB   signals
  __shared__ __align__(16) double buf[8 * NA];   // 32 KB  Dn chunk, then h_bar[8][512]
  __shared__ float  zout[NC][8];                 // 2 KB   z_dl staging
  __shared__ double wsq[8];                      // per-signal sq-error sums
  const int t = threadIdx.x, lane = t & 63, wv = t >> 6;
  const int m0 = blockIdx.x * 8;
  const int bh = m0 >> 6, b = bh >> 6, h = bh & 63, w0 = m0 & 63;
  const size_t zbase = (size_t)b * 262144 + (size_t)h * 64 + w0;

  // load 8 signals (shared (b,h) row, w in [w0,w0+8))
  for (int j = t; j < 8 * NC; j += 256) {
    int c = j >> 3, s = j & 7;
    xs[s][c] = z[zbase + (size_t)c * 4096 + s];
  }

  // ---- phase 1: f64 h_bar GEMM, Dn staged through LDS in 8-row chunks
  double acc[2][8];
#pragma unroll
  for (int s = 0; s < 2; ++s)
#pragma unroll
    for (int i = 0; i < 8; ++i) acc[s][i] = 0.0;

  const double2* Dn2 = (const double2*)Dn;
  double2* buf2 = (double2*)buf;
  for (int ch = 0; ch < 8; ++ch) {
    __syncthreads();                       // previous chunk fully consumed
#pragma unroll
    for (int p = 0; p < 8; ++p) {          // 2048 double2 per chunk, coalesced
      int j = p * 256 + t;
      buf2[j] = Dn2[ch * 2048 + j];
    }
    __syncthreads();
#pragma unroll
    for (int c8 = 0; c8 < 8; ++c8) {
      int c = ch * 8 + c8;
      double x0 = (double)xs[wv * 2 + 0][c];
      double x1 = (double)xs[wv * 2 + 1][c];
#pragma unroll
      for (int i = 0; i < 4; ++i) {
        double2 dv = buf2[c8 * 256 + (i << 6) + lane];
        acc[0][i * 2]     += x0 * dv.x; acc[0][i * 2 + 1] += x0 * dv.y;
        acc[1][i * 2]     += x1 * dv.x; acc[1][i * 2 + 1] += x1 * dv.y;
      }
    }
  }
  __syncthreads();                         // all waves done reading Dn chunks
  // park h_bar in LDS (per-wave region; only read back by the owning wave)
#pragma unroll
  for (int si = 0; si < 2; ++si)
#pragma unroll
    for (int i = 0; i < 4; ++i) {
      double2 v; v.x = acc[si][i * 2]; v.y = acc[si][i * 2 + 1];
      buf2[(size_t)(wv * 2 + si) * 256 + (i << 6) + lane] = v;
    }

  // ---- phase 2: OMP, one wave per signal (2 sequential per wave)
#pragma unroll
  for (int si = 0; si < 2; ++si) {
    const int sig = wv * 2 + si, m = m0 + sig;
    const double*  hbs = buf  + (size_t)sig * NA;   // parked h_bar (atom-indexed)
    const double2* hb2 = buf2 + (size_t)sig * 256;  // same, as double2
    double h8[8];
#pragma unroll
    for (int i = 0; i < 8; ++i) h8[i] = acc[si][i];  // acc dies here
    unsigned msk = 0xFFu;
    int I[KS];
    double Lm[15], rd[KS], gam[KS], hbI[KS];

#pragma unroll
    for (int kk = 0; kk < KS; ++kk) {
      // argmax |h|*mask; first-occurrence (smallest global index) tie-break
      double bv = -1.0; int bn = 0;
#pragma unroll
      for (int s = 0; s < 8; ++s) {
        int a = ((s >> 1) << 7) + 2 * lane + (s & 1);
        double v = ((msk >> s) & 1u) ? fabs(h8[s]) : 0.0;
        if (v > bv || (v == bv && a < bn)) { bv = v; bn = a; }
      }
#pragma unroll
      for (int off = 1; off < 64; off <<= 1) {
        double ov = __shfl_xor(bv, off);
        int    on = __shfl_xor(bn, off);
        if (ov > bv || (ov == bv && on < bn)) { bv = ov; bn = on; }
      }
      const int idx = bn;                              // wave-uniform
      if (((idx & 127) >> 1) == lane)
        msk &= ~(1u << ((((idx >> 7)) << 1) | (idx & 1)));

      hbI[kk] = hbs[idx];                              // LDS broadcast read
      I[kk] = idx;

      // Cholesky update (replicated on all lanes; reciprocal-diag solves)
      if (kk == 0) {
        Lm[0] = 1.0; rd[0] = 1.0;
      } else {
        double Gc[4], w_[4];
#pragma unroll
        for (int j = 0; j < 4; ++j) if (j < kk) Gc[j] = G[(size_t)I[j] * NA + idx];
#pragma unroll
        for (int i = 0; i < 4; ++i) if (i < kk) {
          double ssum = Gc[i];
#pragma unroll
          for (int j = 0; j < 4; ++j) if (j < i) ssum -= Lm[i*(i+1)/2 + j] * w_[j];
          w_[i] = ssum * rd[i];
        }
        double ww = 0.0;
#pragma unroll
        for (int i = 0; i < 4; ++i) if (i < kk) ww += w_[i] * w_[i];
        double corner = sqrt(fmax(1.0 - ww, 1e-12));
#pragma unroll
        for (int j = 0; j < 4; ++j) if (j < kk) Lm[kk*(kk+1)/2 + j] = w_[j];
        Lm[kk*(kk+1)/2 + kk] = corner;
        rd[kk] = 1.0 / corner;
      }

      // gamma = cho_solve((L, lower), h_bar[I])
      double y[KS];
#pragma unroll
      for (int i = 0; i < KS; ++i) if (i <= kk) {
        double b_ = hbI[i];
#pragma unroll
        for (int j = 0; j < KS; ++j) if (j < i) b_ -= Lm[i*(i+1)/2 + j] * y[j];
        y[i] = b_ * rd[i];
      }
#pragma unroll
      for (int i = KS - 1; i >= 0; --i) if (i <= kk) {
        double g_ = y[i];
#pragma unroll
        for (int j = 0; j < KS; ++j) if (j > i && j <= kk) g_ -= Lm[j*(j+1)/2 + i] * gam[j];
        gam[i] = g_ * rd[i];
      }

      // h = h_bar - sum_j gam_j * G[I_j]  (base from LDS, rows streamed from L2)
      if (kk < 4) {
#pragma unroll
        for (int i = 0; i < 4; ++i) {
          double2 hv = hb2[(i << 6) + lane];
          h8[i * 2] = hv.x; h8[i * 2 + 1] = hv.y;
        }
#pragma unroll
        for (int j = 0; j < 4; ++j) if (j <= kk) {
          const double2* g2 = (const double2*)(G + (size_t)I[j] * NA);
          const double gj = gam[j];
#pragma unroll
          for (int i = 0; i < 4; ++i) {
            double2 g = g2[(i << 6) + lane];
            h8[i * 2]     -= gj * g.x;
            h8[i * 2 + 1] -= gj * g.y;
          }
        }
      }
    }

    // ---- epilogue for this signal
    double r = 0.0;
#pragma unroll
    for (int j = 0; j < KS; ++j) r += gam[j] * DnT[(size_t)I[j] * NC + lane];
    const double e = (double)xs[sig][lane];
    const double d = r - e;                      // z_dl - z_e
    zout[lane][sig] = (float)(e + d);            // z_e + (z_dl - z_e)
    double sq = d * d;
#pragma unroll
    for (int off = 1; off < 64; off <<= 1) sq += __shfl_xor(sq, off);
    if (lane == 0) wsq[sig] = sq;

    // support / coeffs: constant-index selection chains only
    if (lane < KS) {
      int    iv = I[0];
      double gv = gam[0];
      if (lane == 1) { iv = I[1]; gv = gam[1]; }
      if (lane == 2) { iv = I[2]; gv = gam[2]; }
      if (lane == 3) { iv = I[3]; gv = gam[3]; }
      if (lane == 4) { iv = I[4]; gv = gam[4]; }
      out[OUT_SUP + (size_t)m * KS + lane] = (float)iv;
      out[OUT_COF + (size_t)m * KS + lane] = (float)gv;
    }
  }

  __syncthreads();
  // coalesced z_dl store: [c][s] tiles, 32B segments
  for (int j = t; j < 8 * NC; j += 256) {
    int c = j >> 3, s = j & 7;
    out[zbase + (size_t)c * 4096 + s] = zout[c][s];
  }
  if (t == 0) {
    double ssum = 0.0;
#pragma unroll
    for (int i = 0; i < 8; ++i) ssum += wsq[i];
    atomicAdd(accum, ssum);
  }
}

__global__ void final_kernel(const double* __restrict__ accum, float* __restrict__ out) {
  double mse = *accum / 2097152.0;
  out[OUT_LOSS] = (float)(mse + 0.25 * mse);
}

extern "C" void kernel_launch(void* const* d_in, const int* in_sizes, int n_in,
                              void* d_out, int out_size, void* d_ws, size_t ws_size,
                              hipStream_t stream) {
  const float* z_e = (const float*)d_in[0];
  const float* dic = (const float*)d_in[1];
  float* out = (float*)d_out;
  double* ws = (double*)d_ws;
  double* Dn   = ws + WS_DN;
  double* DnT  = ws + WS_DNT;
  double* G    = ws + WS_G;
  double* accu = ws + WS_ACC;

  hipLaunchKernelGGL(norm_kernel,  dim3(1),    dim3(512), 0, stream, dic, Dn, DnT);
  hipLaunchKernelGGL(gram_kernel,  dim3(NA),   dim3(NA),  0, stream, Dn, G, accu);
  hipLaunchKernelGGL(omp_kernel,   dim3(4096), dim3(256), 0, stream,
                     z_e, Dn, DnT, G, out, accu);
  hipLaunchKernelGGL(final_kernel, dim3(1),    dim3(1),   0, stream, accu, out);
}